// Round 1
// 142.548 us; speedup vs baseline: 1.0639x; 1.0639x over previous
//
#include <hip/hip_runtime.h>
#include <hip/hip_fp16.h>

static constexpr int Hh = 384;
static constexpr int Ww = 1280;
static constexpr int HW = Hh * Ww;            // 491520
static constexpr int NPIX = 2 * HW;           // 983040
static constexpr int TILE = 32;               // output tile side
static constexpr int S = 6;                   // fused Jacobi steps per launch
static constexpr int R = TILE + 2 * S;        // 44: region side incl. halo
static constexpr int RR = R * R;              // 1936
static constexpr int ISIDE = R - 2;           // 42: interior side
static constexpr int NINT = ISIDE * ISIDE;    // 1764 interior pixels
static constexpr int BLOCK = 256;
static constexpr int PPQ = (RR + BLOCK - 1) / BLOCK;    // 8 region px / thread
static constexpr int PPI = (NINT + BLOCK - 1) / BLOCK;  // 7 interior px / thread
static constexpr int TI = Hh / TILE;          // 12
static constexpr int TJ = Ww / TILE;          // 40
static constexpr int GRID = 2 * TI * TJ;      // 960 tiles (960 % 8 == 0)
static constexpr int NXCD = 8;
static constexpr int CHUNK = GRID / NXCD;     // 120 = 3 tile-rows: contiguous stripe/XCD
static constexpr float EPSF = 1e-9f;

// k order matches reference PADS: (di,dj) =
// k:   0       1       2       3       4       5       6       7
//    (+1,+1) (+1,0) (+1,-1) (0,+1) (0,-1) (-1,+1) (-1,0) (-1,-1)
__device__ __constant__ int DI_c[8] = { 1, 1, 1, 0, 0, -1, -1, -1 };
__device__ __constant__ int DJ_c[8] = { 1, 0, -1, 1, -1, 1, 0, -1 };

// Precompute per pixel: w'_k (fp16, zeroed where sparse-clamped) and
// C = m ? raw : (1-gate_sum)*raw. Each step is then d' = C + sum w'_k d_k.
__global__ void affinity_norm(const float* __restrict__ g,
                              const float* __restrict__ raw,
                              const float* __restrict__ sparse,
                              __half* __restrict__ wbuf,
                              float* __restrict__ cbuf) {
    int idx = blockIdx.x * blockDim.x + threadIdx.x;
    if (idx >= NPIX) return;
    int b = idx / HW;
    int r = idx - b * HW;
    int i = r / Ww;
    int j = r - i * Ww;

    const float* gb = g + (size_t)b * 8 * HW;
    float v[8];
    float a = EPSF;
#pragma unroll
    for (int k = 0; k < 8; k++) {
        int ii = i + DI_c[k], jj = j + DJ_c[k];
        float gv = 0.0f;
        if (ii >= 0 && ii < Hh && jj >= 0 && jj < Ww)
            gv = gb[k * HW + ii * Ww + jj];
        v[k] = gv;
        a += fabsf(gv);
    }
    float inv = 1.0f / a, gs = 0.0f;
#pragma unroll
    for (int k = 0; k < 8; k++) { v[k] *= inv; gs += v[k]; }

    float rawv = raw[idx];
    bool m = sparse[idx] > 0.0f;   // sparse >= 0 always; sign(s)==1 iff s>0
    cbuf[idx] = m ? rawv : (1.0f - gs) * rawv;
    __half wv[8];
#pragma unroll
    for (int k = 0; k < 8; k++) wv[k] = __float2half(m ? 0.0f : v[k]);
    *(float4*)(wbuf + (size_t)idx * 8) = *(const float4*)wv;
}

// Fused S Jacobi steps via overlapped tiling. Block owns a 44x44 region
// (32x32 valid center + halo 6). d ping-pongs in LDS.
//
// Round-N changes vs previous version:
//  1. Weights converted fp16->fp32 ONCE at stage (56 VGPR) — removes the
//     8 v_cvt per px per step that made the step loop VALU-bound.
//  2. Edge ring staged into BOTH LDS buffers once; steps process interior
//     only (no edgemask branch, no per-step copies).
//  3. Shrinking active set: a ring-r pixel's value is only consumed through
//     step r+1, so step s only computes pixels with ring >= s:
//     6x1764 px-steps -> sum (44-2s)^2 = 8284 (-22% LDS BW + VALU).
//  4. XCD-aware bijective block swizzle (960 = 8*120) so each XCD's private
//     L2 sees one contiguous 3-tile-row stripe of wbuf/cbuf/din.
__global__ __launch_bounds__(BLOCK, 4) void fused_steps(
    const __half* __restrict__ wbuf, const float* __restrict__ cbuf,
    const float* __restrict__ din, float* __restrict__ dout)
{
    __shared__ float sd[2][RR];

    const int tid = threadIdx.x;
    // XCD swizzle: hardware round-robins blockIdx%8 across XCDs; give each
    // XCD a contiguous chunk of tiles instead.
    int bx = (blockIdx.x % NXCD) * CHUNK + blockIdx.x / NXCD;
    const int tj = bx % TJ; bx /= TJ;
    const int ti = bx % TI;
    const int b  = bx / TI;
    const int oi = ti * TILE - S;          // region origin (image coords)
    const int oj = tj * TILE - S;

    // --- stage d0 for the whole region; ring pixels into both buffers
    // (their value is frozen for all steps = copy-forward semantics) ---
#pragma unroll
    for (int q = 0; q < PPQ; q++) {
        int p = tid + q * BLOCK;
        if (p < RR) {
            int ri = p / R, rj = p - ri * R;
            int gic = min(max(oi + ri, 0), Hh - 1);
            int gjc = min(max(oj + rj, 0), Ww - 1);
            float v = din[b * HW + gic * Ww + gjc];
            sd[0][p] = v;
            if (ri == 0 || ri == R - 1 || rj == 0 || rj == R - 1)
                sd[1][p] = v;
        }
    }

    // --- stage weights (as fp32) + C for interior pixels ---
    float w[PPI][8];
    float C[PPI];
    int   pp[PPI];
    int   rng[PPI];
#pragma unroll
    for (int q = 0; q < PPI; q++) {
        int pi = tid + q * BLOCK;
        if (pi < NINT) {
            int r0 = pi / ISIDE;
            int ri = 1 + r0, rj = 1 + (pi - r0 * ISIDE);
            int p = ri * R + rj;
            pp[q]  = p;
            rng[q] = min(min(ri, R - 1 - ri), min(rj, R - 1 - rj));
            int gic = min(max(oi + ri, 0), Hh - 1);
            int gjc = min(max(oj + rj, 0), Ww - 1);
            int idx = b * HW + gic * Ww + gjc;
            float4 wv = *(const float4*)(wbuf + (size_t)idx * 8);
            const __half2* wh = (const __half2*)&wv;
            float2 w01 = __half22float2(wh[0]);
            float2 w23 = __half22float2(wh[1]);
            float2 w45 = __half22float2(wh[2]);
            float2 w67 = __half22float2(wh[3]);
            w[q][0] = w01.x; w[q][1] = w01.y; w[q][2] = w23.x; w[q][3] = w23.y;
            w[q][4] = w45.x; w[q][5] = w45.y; w[q][6] = w67.x; w[q][7] = w67.y;
            C[q] = cbuf[idx];
        } else {
            rng[q] = 0;          // never active
            pp[q] = 0;
        }
    }
    __syncthreads();

    // --- steps 1..S-1 in LDS; step s touches only ring >= s ---
    int cur = 0;
#pragma unroll
    for (int s = 1; s < S; s++) {
        const float* s0 = sd[cur];
        float* s1 = sd[cur ^ 1];
#pragma unroll
        for (int q = 0; q < PPI; q++) {
            if (rng[q] >= s) {
                int p = pp[q];
                float v = C[q]
                    + w[q][0] * s0[p + R + 1] + w[q][1] * s0[p + R]
                    + w[q][2] * s0[p + R - 1] + w[q][3] * s0[p + 1]
                    + w[q][4] * s0[p - 1]     + w[q][5] * s0[p - R + 1]
                    + w[q][6] * s0[p - R]     + w[q][7] * s0[p - R - 1];
                s1[p] = v;
            }
        }
        __syncthreads();
        cur ^= 1;
    }

    // --- final step: ring >= S is exactly the valid 32x32 center ---
    const float* s0 = sd[cur];
#pragma unroll
    for (int q = 0; q < PPI; q++) {
        if (rng[q] >= S) {
            int p = pp[q];
            float v = C[q]
                + w[q][0] * s0[p + R + 1] + w[q][1] * s0[p + R]
                + w[q][2] * s0[p + R - 1] + w[q][3] * s0[p + 1]
                + w[q][4] * s0[p - 1]     + w[q][5] * s0[p - R + 1]
                + w[q][6] * s0[p - R]     + w[q][7] * s0[p - R - 1];
            int ri = p / R, rj = p - ri * R;
            dout[b * HW + (oi + ri) * Ww + (oj + rj)] = v;
        }
    }
}

extern "C" void kernel_launch(void* const* d_in, const int* in_sizes, int n_in,
                              void* d_out, int out_size, void* d_ws, size_t ws_size,
                              hipStream_t stream) {
    const float* guidance = (const float*)d_in[0];
    const float* blur     = (const float*)d_in[1];
    const float* sparse   = (const float*)d_in[2];
    float* out = (float*)d_out;

    char* ws = (char*)d_ws;
    float* bufA = (float*)ws;
    float* bufB = bufA + NPIX;
    __half* wbuf = (__half*)(bufB + NPIX);          // NPIX*8 fp16 = 15.7 MB
    float*  cbuf = (float*)(wbuf + (size_t)NPIX * 8);

    const int threads = 256;
    const int blocks = (NPIX + threads - 1) / threads;
    affinity_norm<<<blocks, threads, 0, stream>>>(guidance, blur, sparse, wbuf, cbuf);

    // 24 steps = 4 launches x 6 fused steps
    fused_steps<<<GRID, BLOCK, 0, stream>>>(wbuf, cbuf, blur, bufA);
    fused_steps<<<GRID, BLOCK, 0, stream>>>(wbuf, cbuf, bufA, bufB);
    fused_steps<<<GRID, BLOCK, 0, stream>>>(wbuf, cbuf, bufB, bufA);
    fused_steps<<<GRID, BLOCK, 0, stream>>>(wbuf, cbuf, bufA, out);
}